// Round 4
// baseline (251.238 us; speedup 1.0000x reference)
//
#include <hip/hip_runtime.h>

#define HORIZON 2048
#define B_TOTAL 4096
#define T_OUT 2047

typedef float v2f __attribute__((ext_vector_type(2)));

// Hardware transcendentals (v_exp_f32 = 2^x, v_rcp_f32 = 1/x, ~1 ulp)
__device__ __forceinline__ float hw_exp2(float x) {
    float r;
    asm("v_exp_f32 %0, %1" : "=v"(r) : "v"(x));
    return r;
}
__device__ __forceinline__ float hw_rcp(float x) {
    float r;
    asm("v_rcp_f32 %0, %1" : "=v"(r) : "v"(x));
    return r;
}

// DPP-mapped move (VALU pipe); GCNDPPCombine fuses mov_dpp+add into v_add_f32_dpp
template<int CTRL>
__device__ __forceinline__ float dpp_mov(float v) {
    return __int_as_float(__builtin_amdgcn_update_dpp(
        0, __float_as_int(v), CTRL, 0xF, 0xF, true));
}

// Sum over each 16-lane DPP row; result uniform across the 16 lanes.
__device__ __forceinline__ float rowsum16(float v) {
    v += dpp_mov<0xB1>(v);   // quad_perm xor1
    v += dpp_mov<0x4E>(v);   // quad_perm xor2
    v += dpp_mov<0x124>(v);  // row_ror:4
    v += dpp_mov<0x128>(v);  // row_ror:8
    return v;
}

#define K1  2.8853900817779268f    // 2*log2(e): tanh(a) = 1 - 2/(2^(K1*a)+1)
#define CS -24.04491734814939f     // -log2(e)/0.06: sigmoid(z/tau) = 1/(1+2^(CS*z))
#define ACLAMP 60.0f               // exp2-arg clamp so (1+eA)(1+eB) stays finite

__global__ __launch_bounds__(64) void thermostat_scan4(
    const float* __restrict__ d,
    const float* __restrict__ W1,
    const float* __restrict__ b1,
    const float* __restrict__ W2,
    const float* __restrict__ b2,
    float* __restrict__ xs,
    float* __restrict__ us)
{
    const int lane = threadIdx.x;        // 0..63
    const int sub  = lane >> 4;          // batch row within wave (0..3)
    const int pos  = lane & 15;          // lane position within 16-row
    const int grow = blockIdx.x * 4 + sub;

    const float* drow = d + (size_t)grow * HORIZON;
    const float4* dv  = (const float4*)drow;

    // Lane owns units j = pos+16k, k=0..3, as pairs p: (k=2p, k=2p+1)
    v2f w10c[2], w11c[2], b1c[2];
    float w20m[4], w21m[4];
    float s20p = 0.f, s21p = 0.f;
#pragma unroll
    for (int p = 0; p < 2; ++p) {
        int j0 = pos + 16 * (2 * p);
        int j1 = pos + 16 * (2 * p + 1);
        w10c[p] = v2f{W1[j0] * K1, W1[j1] * K1};
        w11c[p] = v2f{W1[64 + j0] * K1, W1[64 + j1] * K1};
        b1c[p]  = v2f{b1[j0] * K1, b1[j1] * K1};
        float a00 = W2[2 * j0], a01 = W2[2 * j0 + 1];
        float a10 = W2[2 * j1], a11 = W2[2 * j1 + 1];
        w20m[2 * p]     = -2.f * a00;  w21m[2 * p]     = -2.f * a01;
        w20m[2 * p + 1] = -2.f * a10;  w21m[2 * p + 1] = -2.f * a11;
        s20p += a00 + a10;
        s21p += a01 + a11;
    }
    const float zb0  = rowsum16(s20p) + b2[0];
    const float zb1c = (rowsum16(s21p) + b2[1]) * CS;

    float* xs_p = xs + (size_t)grow * T_OUT + pos;
    float* us_p = us + (size_t)grow * T_OUT + pos;

    float4 c0 = dv[0], c1 = dv[1], c2 = dv[2], c3 = dv[3];
    float4 n0 = dv[4], n1 = dv[5], n2 = dv[6], n3 = dv[7];

    float x = c0.x;                 // x0
    float keep_x = x;
    float keep_u = -zb0;            // (+zb0 at store) = 0

    // db[p] = K1*(W1[1,:]*dt + b1) for the CURRENT step, built one step ahead
    v2f db0, db1;
    {
        v2f dt2 = v2f{c0.y, c0.y};  // first executed step is t=1
        db0 = dt2 * w11c[0] + b1c[0];
        db1 = dt2 * w11c[1] + b1c[1];
    }

    const v2f clo = v2f{-ACLAMP, -ACLAMP};
    const v2f chi = v2f{ ACLAMP,  ACLAMP};

    // One scan step. dt = this step's disturbance, dtn = next step's.
    auto step = [&](float dt, float dtn, int slot) {
        // pre-activation (db computed last step, off critical chain)
        v2f x2 = v2f{x, x};
        v2f a0 = x2 * w10c[0] + db0;
        v2f a1 = x2 * w10c[1] + db1;
        a0 = __builtin_elementwise_min(__builtin_elementwise_max(a0, clo), chi);
        a1 = __builtin_elementwise_min(__builtin_elementwise_max(a1, clo), chi);
        // exp
        v2f s0 = v2f{hw_exp2(a0.x), hw_exp2(a0.y)} + v2f{1.f, 1.f};
        v2f s1 = v2f{hw_exp2(a1.x), hw_exp2(a1.y)} + v2f{1.f, 1.f};
        // paired reciprocals: r = 1/(1+e)
        float rp0 = hw_rcp(s0.x * s0.y);
        float rp1 = hw_rcp(s1.x * s1.y);
        float r0 = s0.y * rp0, r1 = s0.x * rp0;
        float r2 = s1.y * rp1, r3 = s1.x * rp1;
        // column partials (z = zb + sum -2 r w)
        float q1 = fmaf(r1, w21m[1], r0 * w21m[0])
                 + fmaf(r3, w21m[3], r2 * w21m[2]);
        float z1 = rowsum16(q1);                  // critical path
        float q0 = fmaf(r1, w20m[1], r0 * w20m[0])
                 + fmaf(r3, w20m[3], r2 * w20m[2]);
        float z0 = rowsum16(q0);
        // work that overlaps the sigmoid's exp/rcp latency:
        float xd = fmaf(0.99f, x, -dt);           // x_new minus the 0.4*ub term
        v2f dtn2 = v2f{dtn, dtn};
        db0 = dtn2 * w11c[0] + b1c[0];            // next step's dt-part
        db1 = dtn2 * w11c[1] + b1c[1];
        // sigmoid
        float ub = hw_rcp(1.f + hw_exp2(fmaf(z1, CS, zb1c)));
        x = fmaf(0.4f, ub, xd);
        // stash
        bool k = (pos == slot);
        keep_x = k ? x : keep_x;
        keep_u = k ? z0 : keep_u;
    };

    // ---- chunk 0: steps t=1..15 (slot 0 holds x0 / 0) ----
    {
        float dt16[16] = {c0.x, c0.y, c0.z, c0.w, c1.x, c1.y, c1.z, c1.w,
                          c2.x, c2.y, c2.z, c2.w, c3.x, c3.y, c3.z, c3.w};
#pragma unroll
        for (int s = 1; s < 16; ++s)
            step(dt16[s], (s < 15) ? dt16[s + 1] : n0.x, s);
        xs_p[0] = keep_x;
        us_p[0] = keep_u + zb0;
    }

    // ---- chunks 1..126 (16 steps each), prefetch chunk c+1 ----
    for (int c = 1; c < 127; ++c) {
        c0 = n0; c1 = n1; c2 = n2; c3 = n3;
        n0 = dv[4 * c + 4]; n1 = dv[4 * c + 5];
        n2 = dv[4 * c + 6]; n3 = dv[4 * c + 7];
        float dt16[16] = {c0.x, c0.y, c0.z, c0.w, c1.x, c1.y, c1.z, c1.w,
                          c2.x, c2.y, c2.z, c2.w, c3.x, c3.y, c3.z, c3.w};
#pragma unroll
        for (int s = 0; s < 16; ++s)
            step(dt16[s], (s < 15) ? dt16[s + 1] : n0.x, s);
        xs_p[c * 16] = keep_x;
        us_p[c * 16] = keep_u + zb0;
    }

    // ---- chunk 127: steps t=2032..2046 (15 steps, slots 0..14) ----
    {
        float dt16[16] = {n0.x, n0.y, n0.z, n0.w, n1.x, n1.y, n1.z, n1.w,
                          n2.x, n2.y, n2.z, n2.w, n3.x, n3.y, n3.z, n3.w};
#pragma unroll
        for (int s = 0; s < 15; ++s)
            step(dt16[s], dt16[s + 1], s);
        if (pos < 15) {
            xs_p[127 * 16] = keep_x;
            us_p[127 * 16] = keep_u + zb0;
        }
    }
}

extern "C" void kernel_launch(void* const* d_in, const int* in_sizes, int n_in,
                              void* d_out, int out_size, void* d_ws, size_t ws_size,
                              hipStream_t stream) {
    const float* d  = (const float*)d_in[0];
    const float* W1 = (const float*)d_in[1];
    const float* b1 = (const float*)d_in[2];
    const float* W2 = (const float*)d_in[3];
    const float* b2 = (const float*)d_in[4];
    float* xs = (float*)d_out;
    float* us = xs + (size_t)B_TOTAL * T_OUT;

    dim3 grid(B_TOTAL / 4);   // 1024 waves, 4 batch rows per wave
    thermostat_scan4<<<grid, 64, 0, stream>>>(d, W1, b1, W2, b2, xs, us);
}

// Round 5
// 250.170 us; speedup vs baseline: 1.0043x; 1.0043x over previous
//
#include <hip/hip_runtime.h>

#define HORIZON 2048
#define B_TOTAL 4096
#define T_OUT 2047

typedef float v2f __attribute__((ext_vector_type(2)));

// Hardware transcendentals (v_exp_f32 = 2^x, v_rcp_f32 = 1/x, ~1 ulp)
__device__ __forceinline__ float hw_exp2(float x) {
    float r;
    asm("v_exp_f32 %0, %1" : "=v"(r) : "v"(x));
    return r;
}
__device__ __forceinline__ float hw_rcp(float x) {
    float r;
    asm("v_rcp_f32 %0, %1" : "=v"(r) : "v"(x));
    return r;
}

// DPP-mapped move (VALU pipe); fuses into v_add_f32_dpp
template<int CTRL>
__device__ __forceinline__ float dpp_mov(float v) {
    return __int_as_float(__builtin_amdgcn_update_dpp(
        0, __float_as_int(v), CTRL, 0xF, 0xF, true));
}

// Sum over each 16-lane DPP row; result uniform across the 16 lanes.
__device__ __forceinline__ float rowsum16(float v) {
    v += dpp_mov<0xB1>(v);   // quad_perm xor1
    v += dpp_mov<0x4E>(v);   // quad_perm xor2
    v += dpp_mov<0x124>(v);  // row_ror:4
    v += dpp_mov<0x128>(v);  // row_ror:8
    return v;
}

#define CS -24.04491734814939f   // -log2(e)/0.06: sigmoid(z/tau)=1/(1+2^(CS*z))
#define ACL 4.8f                 // tanh input clamp for the Pade(7,6) rational

// clamp via v_med3_f32
__device__ __forceinline__ float clampA(float a) {
    return fminf(fmaxf(a, -ACL), ACL);
}

__global__ __launch_bounds__(64) void thermostat_scan4(
    const float* __restrict__ d,
    const float* __restrict__ W1,
    const float* __restrict__ b1,
    const float* __restrict__ W2,
    const float* __restrict__ b2,
    float* __restrict__ xs,
    float* __restrict__ us)
{
    const int lane = threadIdx.x;        // 0..63
    const int sub  = lane >> 4;          // batch row within wave (0..3)
    const int pos  = lane & 15;          // lane position within 16-row
    const int grow = blockIdx.x * 4 + sub;

    const float* drow = d + (size_t)grow * HORIZON;
    const float4* dv  = (const float4*)drow;

    // Lane owns units j = pos+16k, k=0..3, paired p0:(k=0,1) p1:(k=2,3)
    v2f w10[2], w11[2], b1v[2], w20v[2], w21v[2];
#pragma unroll
    for (int p = 0; p < 2; ++p) {
        int j0 = pos + 32 * p;
        int j1 = j0 + 16;
        w10[p]  = v2f{W1[j0], W1[j1]};
        w11[p]  = v2f{W1[64 + j0], W1[64 + j1]};
        b1v[p]  = v2f{b1[j0], b1[j1]};
        w20v[p] = v2f{W2[2 * j0], W2[2 * j1]};
        w21v[p] = v2f{W2[2 * j0 + 1], W2[2 * j1 + 1]};
    }
    const float zb0  = b2[0];
    const float zb1c = b2[1] * CS;

    float* xs_p = xs + (size_t)grow * T_OUT + pos;
    float* us_p = us + (size_t)grow * T_OUT + pos;

    float4 c0 = dv[0], c1 = dv[1], c2 = dv[2], c3 = dv[3];
    float4 n0 = dv[4], n1 = dv[5], n2 = dv[6], n3 = dv[7];

    float x = c0.x;                 // x0
    float keep_x = x;
    float keep_u = -zb0;            // (+zb0 at store) = 0

    // db[p] = W1[1,:]*dt + b1 for the CURRENT step, built one step ahead
    v2f db0, db1;
    {
        v2f dt2 = v2f{c0.y, c0.y};
        db0 = dt2 * w11[0] + b1v[0];
        db1 = dt2 * w11[1] + b1v[1];
    }

    auto step = [&](float dt, float dtn, int slot) {
        // layer-1 pre-activation (dt part precomputed last step)
        v2f x2 = v2f{x, x};
        v2f a0 = x2 * w10[0] + db0;
        v2f a1 = x2 * w10[1] + db1;
        a0 = v2f{clampA(a0.x), clampA(a0.y)};
        a1 = v2f{clampA(a1.x), clampA(a1.y)};
        // tanh via Pade(7,6): tanh(a) = a*num(y)/den(y), y=a^2
        v2f y0 = a0 * a0, y1 = a1 * a1;
        v2f nu0 = ((y0 + 378.f) * y0 + 17325.f) * y0 + 135135.f;
        v2f nu1 = ((y1 + 378.f) * y1 + 17325.f) * y1 + 135135.f;
        v2f de0 = (y0 * 28.f + 3150.f) * y0 + 62370.f; de0 = de0 * y0 + 135135.f;
        v2f de1 = (y1 * 28.f + 3150.f) * y1 + 62370.f; de1 = de1 * y1 + 135135.f;
        v2f na0 = nu0 * a0, na1 = nu1 * a1;
        // paired reciprocals: one rcp per 2 units
        float rp0 = hw_rcp(de0.x * de0.y);
        float rp1 = hw_rcp(de1.x * de1.y);
        v2f h0 = v2f{na0.x * de0.y, na0.y * de0.x} * rp0;
        v2f h1 = v2f{na1.x * de1.y, na1.y * de1.x} * rp1;
        // layer-2 partials: z = b2 + sum_j h_j w2_j
        v2f m1 = h0 * w21v[0]; m1 = h1 * w21v[1] + m1;
        float z1 = rowsum16(m1.x + m1.y);         // critical path
        v2f m0 = h0 * w20v[0]; m0 = h1 * w20v[1] + m0;
        float z0 = rowsum16(m0.x + m0.y);         // off critical path
        // overlap sigmoid latency with next-step prep
        float xd = fmaf(0.99f, x, -dt);
        v2f dtn2 = v2f{dtn, dtn};
        db0 = dtn2 * w11[0] + b1v[0];
        db1 = dtn2 * w11[1] + b1v[1];
        // u_bin = sigmoid(z1full/tau) = 1/(1+2^(CS*z1+zb1c)) — exact path
        float ub = hw_rcp(1.f + hw_exp2(fmaf(z1, CS, zb1c)));
        x = fmaf(0.4f, ub, xd);
        // stash outputs in the owning lane
        bool k = (pos == slot);
        keep_x = k ? x : keep_x;
        keep_u = k ? z0 : keep_u;
    };

    // ---- chunk 0: steps t=1..15 (slot 0 holds x0 / 0) ----
    {
        float dt16[16] = {c0.x, c0.y, c0.z, c0.w, c1.x, c1.y, c1.z, c1.w,
                          c2.x, c2.y, c2.z, c2.w, c3.x, c3.y, c3.z, c3.w};
#pragma unroll
        for (int s = 1; s < 16; ++s)
            step(dt16[s], (s < 15) ? dt16[s + 1] : n0.x, s);
        xs_p[0] = keep_x;
        us_p[0] = keep_u + zb0;
    }

    // ---- chunks 1..126 (16 steps each), prefetch chunk c+1 ----
    for (int c = 1; c < 127; ++c) {
        c0 = n0; c1 = n1; c2 = n2; c3 = n3;
        n0 = dv[4 * c + 4]; n1 = dv[4 * c + 5];
        n2 = dv[4 * c + 6]; n3 = dv[4 * c + 7];
        float dt16[16] = {c0.x, c0.y, c0.z, c0.w, c1.x, c1.y, c1.z, c1.w,
                          c2.x, c2.y, c2.z, c2.w, c3.x, c3.y, c3.z, c3.w};
#pragma unroll
        for (int s = 0; s < 16; ++s)
            step(dt16[s], (s < 15) ? dt16[s + 1] : n0.x, s);
        xs_p[c * 16] = keep_x;
        us_p[c * 16] = keep_u + zb0;
    }

    // ---- chunk 127: steps t=2032..2046 (15 steps, slots 0..14) ----
    {
        float dt16[16] = {n0.x, n0.y, n0.z, n0.w, n1.x, n1.y, n1.z, n1.w,
                          n2.x, n2.y, n2.z, n2.w, n3.x, n3.y, n3.z, n3.w};
#pragma unroll
        for (int s = 0; s < 15; ++s)
            step(dt16[s], dt16[s + 1], s);
        if (pos < 15) {
            xs_p[127 * 16] = keep_x;
            us_p[127 * 16] = keep_u + zb0;
        }
    }
}

extern "C" void kernel_launch(void* const* d_in, const int* in_sizes, int n_in,
                              void* d_out, int out_size, void* d_ws, size_t ws_size,
                              hipStream_t stream) {
    const float* d  = (const float*)d_in[0];
    const float* W1 = (const float*)d_in[1];
    const float* b1 = (const float*)d_in[2];
    const float* W2 = (const float*)d_in[3];
    const float* b2 = (const float*)d_in[4];
    float* xs = (float*)d_out;
    float* us = xs + (size_t)B_TOTAL * T_OUT;

    dim3 grid(B_TOTAL / 4);   // 1024 waves, 4 batch rows per wave
    thermostat_scan4<<<grid, 64, 0, stream>>>(d, W1, b1, W2, b2, xs, us);
}